// Round 2
// baseline (7733.871 us; speedup 1.0000x reference)
//
#include <hip/hip_runtime.h>
#include <cstdint>
#include <cstddef>

// ============================================================================
// disciminativeAno: fp32 VAE forward + Otsu mask on gfx950.
// All conv/FC kernels: LDS-staged activations (XOR bank swizzle), wave-uniform
// scalar weight loads (readfirstlane => s_load), 16-32 acc regs per thread.
// Workspace is chunked over the batch; chunk size adapts to ws_size.
// ============================================================================

// ---------------------------------------------------------------------------
// conv1: x[C,32,32,3] -> h1[C,16,16,32], 5x5 s2 SAME (pad lo=1), relu(+b)*s+o
// ---------------------------------------------------------------------------
__global__ __launch_bounds__(256) void k_conv1(const float* __restrict__ x,
    const float* __restrict__ w, const float* __restrict__ bb,
    const float* __restrict__ sc, const float* __restrict__ of,
    float* __restrict__ out) {
  const int b = blockIdx.x;
  const int pos = threadIdx.x;          // 16x16 output positions
  const int oy = pos >> 4, ox = pos & 15;
  float acc[32];
#pragma unroll
  for (int c = 0; c < 32; ++c) acc[c] = 0.f;
  const float* xb = x + (size_t)b * 3072;
#pragma unroll 1
  for (int ky = 0; ky < 5; ++ky) {
    const int iy = 2 * oy - 1 + ky;
    if ((unsigned)iy >= 32u) continue;
#pragma unroll 1
    for (int kx = 0; kx < 5; ++kx) {
      const int ix = 2 * ox - 1 + kx;
      if ((unsigned)ix >= 32u) continue;
      const float* xp = xb + (iy * 32 + ix) * 3;
#pragma unroll
      for (int ci = 0; ci < 3; ++ci) {
        const float v = xp[ci];
        const float* wp = w + ((ky * 5 + kx) * 3 + ci) * 32;
#pragma unroll
        for (int c = 0; c < 32; ++c) acc[c] = fmaf(v, wp[c], acc[c]);
      }
    }
  }
  float* op = out + ((size_t)b * 256 + pos) * 32;
#pragma unroll
  for (int c = 0; c < 32; ++c) {
    const float v = fmaxf(acc[c] + bb[c], 0.f);
    op[c] = v * sc[c] + of[c];
  }
}

// ---------------------------------------------------------------------------
// conv2: h1[C,16,16,32] -> h2[C,8,8,64], 5x5 s2 SAME (pad lo=1)
// ---------------------------------------------------------------------------
__global__ __launch_bounds__(256) void k_conv2(const float* __restrict__ in,
    const float* __restrict__ w, const float* __restrict__ bb,
    const float* __restrict__ sc, const float* __restrict__ of,
    float* __restrict__ out) {
  __shared__ float tile[2 * 8192];       // 64 KB, XOR swizzled
  const int b0 = blockIdx.x * 2;
  const int tid = threadIdx.x;
  for (int f4 = tid; f4 < 4096; f4 += 256) {
    const int img = f4 >> 11, rem = f4 & 2047;
    const int pix = rem >> 3, c4 = (rem & 7) << 2;
    const float4 v = ((const float4*)(in + (size_t)(b0 + img) * 8192))[rem];
    const int s = ((pix >> 4) * 5 + (pix & 15)) & 31;
    float* dst = &tile[img * 8192 + pix * 32];
    dst[(c4 + 0) ^ s] = v.x; dst[(c4 + 1) ^ s] = v.y;
    dst[(c4 + 2) ^ s] = v.z; dst[(c4 + 3) ^ s] = v.w;
  }
  __syncthreads();
  const int lane = tid & 63;
  const int img = __builtin_amdgcn_readfirstlane(tid >> 7);
  const int ch  = __builtin_amdgcn_readfirstlane(((tid >> 6) & 1) * 32);
  const int oy = lane >> 3, ox = lane & 7;
  float acc[32];
#pragma unroll
  for (int c = 0; c < 32; ++c) acc[c] = 0.f;
  const float* tb = &tile[img * 8192];
#pragma unroll 1
  for (int ky = 0; ky < 5; ++ky) {
    const int iy = 2 * oy - 1 + ky;
#pragma unroll 1
    for (int kx = 0; kx < 5; ++kx) {
      const int ix = 2 * ox - 1 + kx;
      const bool valid = ((unsigned)iy < 16u) && ((unsigned)ix < 16u);
      const int pix = valid ? (iy * 16 + ix) : 0;
      const int s = ((pix >> 4) * 5 + (pix & 15)) & 31;
      const float* tp = tb + pix * 32;
      const float* wrow = w + ((ky * 5 + kx) * 32) * 64 + ch;
#pragma unroll 4
      for (int ci = 0; ci < 32; ++ci) {
        float v = tp[ci ^ s];
        v = valid ? v : 0.f;
        const float* wp = wrow + ci * 64;
#pragma unroll
        for (int c = 0; c < 32; ++c) acc[c] = fmaf(v, wp[c], acc[c]);
      }
    }
  }
  float* op = out + ((size_t)(b0 + img) * 64 + lane) * 64 + ch;
#pragma unroll
  for (int c = 0; c < 32; ++c) {
    const float v = fmaxf(acc[c] + bb[ch + c], 0.f);
    op[c] = v * sc[ch + c] + of[ch + c];
  }
}

// ---------------------------------------------------------------------------
// conv3: h2[C,8,8,64] -> h3[C,4,4,128], 5x5 s2 SAME (pad lo=1)
// ---------------------------------------------------------------------------
__global__ __launch_bounds__(256) void k_conv3(const float* __restrict__ in,
    const float* __restrict__ w, const float* __restrict__ bb,
    const float* __restrict__ sc, const float* __restrict__ of,
    float* __restrict__ out) {
  __shared__ float tile[4 * 4096];       // 64 KB
  const int b0 = blockIdx.x * 4;
  const int tid = threadIdx.x;
  for (int f4 = tid; f4 < 4096; f4 += 256) {
    const int img = f4 >> 10, rem = f4 & 1023;
    const int pix = rem >> 4, c4 = (rem & 15) << 2;
    const float4 v = ((const float4*)(in + (size_t)(b0 + img) * 4096))[rem];
    const int s = ((pix << 2) + img) & 31;
    float* dst = &tile[img * 4096 + pix * 64];
    dst[(c4 + 0) ^ s] = v.x; dst[(c4 + 1) ^ s] = v.y;
    dst[(c4 + 2) ^ s] = v.z; dst[(c4 + 3) ^ s] = v.w;
  }
  __syncthreads();
  const int lane = tid & 63;
  const int pos = lane & 15, img = lane >> 4;
  const int ch = __builtin_amdgcn_readfirstlane((tid >> 6) * 32);
  const int oy = pos >> 2, ox = pos & 3;
  float acc[32];
#pragma unroll
  for (int c = 0; c < 32; ++c) acc[c] = 0.f;
  const float* tb = &tile[img * 4096];
#pragma unroll 1
  for (int ky = 0; ky < 5; ++ky) {
    const int iy = 2 * oy - 1 + ky;
#pragma unroll 1
    for (int kx = 0; kx < 5; ++kx) {
      const int ix = 2 * ox - 1 + kx;
      const bool valid = ((unsigned)iy < 8u) && ((unsigned)ix < 8u);
      const int pix = valid ? (iy * 8 + ix) : 0;
      const int s = ((pix << 2) + img) & 31;
      const float* tp = tb + pix * 64;
      const float* wrow = w + ((ky * 5 + kx) * 64) * 128 + ch;
#pragma unroll 4
      for (int ci = 0; ci < 64; ++ci) {
        float v = tp[ci ^ s];
        v = valid ? v : 0.f;
        const float* wp = wrow + ci * 128;
#pragma unroll
        for (int c = 0; c < 32; ++c) acc[c] = fmaf(v, wp[c], acc[c]);
      }
    }
  }
  float* op = out + ((size_t)(b0 + img) * 16 + pos) * 128 + ch;
#pragma unroll
  for (int c = 0; c < 32; ++c) {
    const float v = fmaxf(acc[c] + bb[ch + c], 0.f);
    op[c] = v * sc[ch + c] + of[ch + c];
  }
}

// ---------------------------------------------------------------------------
// fc_z: h3[C,2048] -> z[C,128]; z = relu(h@wzm+bzm) + exp(0.5*relu(h@wzl+bzl))*eps
// ---------------------------------------------------------------------------
__global__ __launch_bounds__(256) void k_fcz(const float* __restrict__ h3,
    const float* __restrict__ wzm, const float* __restrict__ bzm,
    const float* __restrict__ wzl, const float* __restrict__ bzl,
    const float* __restrict__ eps, float* __restrict__ z) {
  __shared__ float a[16 * 256];
  const int ib = blockIdx.x * 16;
  const int tid = threadIdx.x;
  const int co = tid & 127;
  const int grp = __builtin_amdgcn_readfirstlane(tid >> 7);
  float am[8], al[8];
#pragma unroll
  for (int i = 0; i < 8; ++i) { am[i] = 0.f; al[i] = 0.f; }
  for (int kc = 0; kc < 2048; kc += 256) {
    __syncthreads();
#pragma unroll
    for (int q = 0; q < 4; ++q) {
      const int f4 = tid + q * 256;
      const int r = f4 >> 6, c4 = (f4 & 63) << 2;
      *(float4*)&a[r * 256 + c4] =
          *(const float4*)&h3[(size_t)(ib + r) * 2048 + kc + c4];
    }
    __syncthreads();
#pragma unroll 4
    for (int k = 0; k < 256; k += 4) {
      float wm[4], wl[4];
#pragma unroll
      for (int q = 0; q < 4; ++q) {
        wm[q] = wzm[(size_t)(kc + k + q) * 128 + co];
        wl[q] = wzl[(size_t)(kc + k + q) * 128 + co];
      }
#pragma unroll
      for (int i = 0; i < 8; ++i) {
        const float4 av = *(const float4*)&a[(grp * 8 + i) * 256 + k];
        am[i] = fmaf(av.x, wm[0], am[i]); am[i] = fmaf(av.y, wm[1], am[i]);
        am[i] = fmaf(av.z, wm[2], am[i]); am[i] = fmaf(av.w, wm[3], am[i]);
        al[i] = fmaf(av.x, wl[0], al[i]); al[i] = fmaf(av.y, wl[1], al[i]);
        al[i] = fmaf(av.z, wl[2], al[i]); al[i] = fmaf(av.w, wl[3], al[i]);
      }
    }
  }
#pragma unroll
  for (int i = 0; i < 8; ++i) {
    const int row = ib + grp * 8 + i;
    const float zm = fmaxf(am[i] + bzm[co], 0.f);
    const float zl = fmaxf(al[i] + bzl[co], 0.f);
    z[(size_t)row * 128 + co] = zm + expf(0.5f * zl) * eps[(size_t)row * 128 + co];
  }
}

// ---------------------------------------------------------------------------
// fc_dec: z[C,128] @ dw[128,8192] + db -> relu -> d[C,8192]
// ---------------------------------------------------------------------------
__global__ __launch_bounds__(256) void k_fcdec(const float* __restrict__ z,
    const float* __restrict__ dw, const float* __restrict__ db,
    float* __restrict__ out) {
  __shared__ float zt[64 * 128];         // 32 KB
  const int bid = blockIdx.x;
  const int m0 = (bid >> 6) * 64;
  const int n0 = (bid & 63) * 128;
  const int tid = threadIdx.x;
#pragma unroll
  for (int q = 0; q < 8; ++q) {
    const int f4 = tid + q * 256;        // 2048 f4
    const int img = f4 >> 5, c4 = (f4 & 31) << 2;
    const float4 v = *(const float4*)&z[(size_t)(m0 + img) * 128 + c4];
    const int s = img & 31;
    float* dst = &zt[img * 128];
    dst[(c4 + 0) ^ s] = v.x; dst[(c4 + 1) ^ s] = v.y;
    dst[(c4 + 2) ^ s] = v.z; dst[(c4 + 3) ^ s] = v.w;
  }
  __syncthreads();
  const int img = tid & 63;
  const int grp = __builtin_amdgcn_readfirstlane(tid >> 6);
  const int nb = n0 + grp * 32;
  float acc[32];
#pragma unroll
  for (int c = 0; c < 32; ++c) acc[c] = 0.f;
  const float* zrow = &zt[img * 128];
  const int s = img & 31;
#pragma unroll 4
  for (int k = 0; k < 128; ++k) {
    const float v = zrow[k ^ s];
    const float* wp = dw + (size_t)k * 8192 + nb;
#pragma unroll
    for (int c = 0; c < 32; ++c) acc[c] = fmaf(v, wp[c], acc[c]);
  }
  float* op = out + (size_t)(m0 + img) * 8192 + nb;
#pragma unroll
  for (int c = 0; c < 32; ++c) op[c] = fmaxf(acc[c] + db[nb + c], 0.f);
}

// ---------------------------------------------------------------------------
// convT1: 1x1 s1: d[C,8,8,128] -> t1[C,8,8,128]
// ---------------------------------------------------------------------------
__global__ __launch_bounds__(256) void k_tconv1(const float* __restrict__ in,
    const float* __restrict__ w, const float* __restrict__ bb,
    const float* __restrict__ sc, const float* __restrict__ of,
    float* __restrict__ out) {
  __shared__ float tile[8192];           // 32 KB
  const int b = blockIdx.x;
  const int tid = threadIdx.x;
#pragma unroll
  for (int q = 0; q < 8; ++q) {
    const int f4 = tid + q * 256;
    const int pix = f4 >> 5, c4 = (f4 & 31) << 2;
    const float4 v = ((const float4*)(in + (size_t)b * 8192))[f4];
    const int s = pix & 31;
    float* dst = &tile[pix * 128];
    dst[(c4 + 0) ^ s] = v.x; dst[(c4 + 1) ^ s] = v.y;
    dst[(c4 + 2) ^ s] = v.z; dst[(c4 + 3) ^ s] = v.w;
  }
  __syncthreads();
  const int pos = tid & 63;
  const int ch = __builtin_amdgcn_readfirstlane((tid >> 6) * 32);
  const float* trow = &tile[pos * 128];
  const int s = pos & 31;
  float acc[32];
#pragma unroll
  for (int c = 0; c < 32; ++c) acc[c] = 0.f;
#pragma unroll 4
  for (int ci = 0; ci < 128; ++ci) {
    const float v = trow[ci ^ s];
    const float* wp = w + ci * 128 + ch;
#pragma unroll
    for (int c = 0; c < 32; ++c) acc[c] = fmaf(v, wp[c], acc[c]);
  }
  float* op = out + ((size_t)b * 64 + pos) * 128 + ch;
#pragma unroll
  for (int c = 0; c < 32; ++c) {
    const float v = fmaxf(acc[c] + bb[ch + c], 0.f);
    op[c] = v * sc[ch + c] + of[ch + c];
  }
}

// ---------------------------------------------------------------------------
// convT2: 3x3 s2 SAME transpose (UNFLIPPED kernel, lhs-dilated, pad (2,1)):
//   out[2j+0] += in[j-1]*w[0] + in[j]*w[2];  out[2j+1] += in[j]*w[1]
// thread = input pos (jy,jx), gathers its 2x2 output block via 9 taps.
// ---------------------------------------------------------------------------
__global__ __launch_bounds__(256) void k_tconv2(const float* __restrict__ in,
    const float* __restrict__ w, const float* __restrict__ bb,
    const float* __restrict__ sc, const float* __restrict__ of,
    float* __restrict__ out) {
  __shared__ float tile[64 * 129];
  const int b = blockIdx.x;
  const int tid = threadIdx.x;
#pragma unroll
  for (int q = 0; q < 8; ++q) {
    const int f4 = tid + q * 256;
    const int pix = f4 >> 5, c4 = (f4 & 31) << 2;
    const float4 v = ((const float4*)(in + (size_t)b * 8192))[f4];
    float* dst = &tile[pix * 129 + c4];
    dst[0] = v.x; dst[1] = v.y; dst[2] = v.z; dst[3] = v.w;
  }
  __syncthreads();
  const int lane = tid & 63;
  const int ch = __builtin_amdgcn_readfirstlane((tid >> 6) * 16);
  const int jy = lane >> 3, jx = lane & 7;
  float acc[4][16];
#pragma unroll
  for (int p = 0; p < 4; ++p)
#pragma unroll
    for (int c = 0; c < 16; ++c) acc[p][c] = 0.f;
  // UNFLIPPED pairing: DY=1<->KY=0, DY=0<->KY=2 (even phase); DY=0<->KY=1 (odd)
  const int DY[9]  = {1,1,0,0,1,0,0,0,0};
  const int DX[9]  = {1,0,1,0,0,0,1,0,0};
  const int KYt[9] = {0,0,2,2,0,2,1,1,1};
  const int KXt[9] = {0,2,0,2,1,1,0,2,1};
  const int PHt[9] = {0,0,0,0,1,1,2,2,3};
#pragma unroll
  for (int t = 0; t < 9; ++t) {
    const int sy = jy - DY[t], sx = jx - DX[t];
    const bool valid = (sy >= 0) && (sx >= 0);
    const int base = valid ? (sy * 8 + sx) * 129 : 0;
    const float* wrow = w + ((KYt[t] * 3 + KXt[t]) * 128) * 64 + ch;
#pragma unroll 4
    for (int ci = 0; ci < 128; ++ci) {
      float v = tile[base + ci];
      v = valid ? v : 0.f;
      const float* wp = wrow + ci * 64;
#pragma unroll
      for (int c = 0; c < 16; ++c)
        acc[PHt[t]][c] = fmaf(v, wp[c], acc[PHt[t]][c]);
    }
  }
#pragma unroll
  for (int py = 0; py < 2; ++py)
#pragma unroll
    for (int px = 0; px < 2; ++px) {
      const int oy = 2 * jy + py, ox = 2 * jx + px;
      float* op = out + (((size_t)b * 16 + oy) * 16 + ox) * 64 + ch;
#pragma unroll
      for (int c = 0; c < 16; ++c) {
        const float v = fmaxf(acc[py * 2 + px][c] + bb[ch + c], 0.f);
        op[c] = v * sc[ch + c] + of[ch + c];
      }
    }
}

// ---------------------------------------------------------------------------
// convT3: 3x3 s2 SAME transpose (unflipped): t2[C,16,16,64] -> t3[C,32,32,32]
// ---------------------------------------------------------------------------
__global__ __launch_bounds__(256) void k_tconv3(const float* __restrict__ in,
    const float* __restrict__ w, const float* __restrict__ bb,
    const float* __restrict__ sc, const float* __restrict__ of,
    float* __restrict__ out) {
  __shared__ float tile[256 * 64];       // 64 KB, XOR swizzled
  const int b = blockIdx.x;
  const int tid = threadIdx.x;
#pragma unroll
  for (int q = 0; q < 16; ++q) {
    const int f4 = tid + q * 256;        // 4096 f4
    const int pix = f4 >> 4, c4 = (f4 & 15) << 2;
    const float4 v = ((const float4*)(in + (size_t)b * 16384))[f4];
    const int s = ((pix >> 4) * 5 + (pix & 15)) & 31;
    float* dst = &tile[pix * 64];
    dst[(c4 + 0) ^ s] = v.x; dst[(c4 + 1) ^ s] = v.y;
    dst[(c4 + 2) ^ s] = v.z; dst[(c4 + 3) ^ s] = v.w;
  }
  __syncthreads();
  const int jy = tid >> 4, jx = tid & 15;
  float acc[4][32];
#pragma unroll
  for (int p = 0; p < 4; ++p)
#pragma unroll
    for (int c = 0; c < 32; ++c) acc[p][c] = 0.f;
  const int DY[9]  = {1,1,0,0,1,0,0,0,0};
  const int DX[9]  = {1,0,1,0,0,0,1,0,0};
  const int KYt[9] = {0,0,2,2,0,2,1,1,1};
  const int KXt[9] = {0,2,0,2,1,1,0,2,1};
  const int PHt[9] = {0,0,0,0,1,1,2,2,3};
#pragma unroll
  for (int t = 0; t < 9; ++t) {
    const int sy = jy - DY[t], sx = jx - DX[t];
    const bool valid = (sy >= 0) && (sx >= 0);
    const int pix = valid ? (sy * 16 + sx) : 0;
    const int s = ((pix >> 4) * 5 + (pix & 15)) & 31;
    const float* tp = &tile[pix * 64];
    const float* wrow = w + ((KYt[t] * 3 + KXt[t]) * 64) * 32;
#pragma unroll 2
    for (int ci = 0; ci < 64; ++ci) {
      float v = tp[ci ^ s];
      v = valid ? v : 0.f;
      const float* wp = wrow + ci * 32;
#pragma unroll
      for (int c = 0; c < 32; ++c)
        acc[PHt[t]][c] = fmaf(v, wp[c], acc[PHt[t]][c]);
    }
  }
#pragma unroll
  for (int py = 0; py < 2; ++py)
#pragma unroll
    for (int px = 0; px < 2; ++px) {
      const int oy = 2 * jy + py, ox = 2 * jx + px;
      float* op = out + (((size_t)b * 32 + oy) * 32 + ox) * 32;
#pragma unroll
      for (int c = 0; c < 32; ++c) {
        const float v = fmaxf(acc[py * 2 + px][c] + bb[c], 0.f);
        op[c] = v * sc[c] + of[c];
      }
    }
}

// ---------------------------------------------------------------------------
// convT4 (3x3 s1 SAME, pad (1,1), unflipped) + sigmoid + per-pixel error.
// ---------------------------------------------------------------------------
__global__ __launch_bounds__(128) void k_tconv4err(const float* __restrict__ t3,
    const float* __restrict__ w, const float* __restrict__ bb,
    const float* __restrict__ x, float* __restrict__ err) {
  __shared__ float tile[32 * 340];       // [ci][row(10)*34 + col] = 43.5 KB
  const int b = blockIdx.x >> 2;
  const int r0 = (blockIdx.x & 3) * 8;
  const int tid = threadIdx.x;
  for (int f4 = tid; f4 < 2560; f4 += 128) {
    const int rr = f4 >> 8, rem = f4 & 255;
    const int px = rem >> 3, c4 = (rem & 7) << 2;
    const int gy = r0 - 1 + rr;
    float4 v = make_float4(0.f, 0.f, 0.f, 0.f);
    if ((unsigned)gy < 32u)
      v = *(const float4*)&t3[(((size_t)b * 32 + gy) * 32 + px) * 32 + c4];
    tile[(c4 + 0) * 340 + rr * 34 + px] = v.x;
    tile[(c4 + 1) * 340 + rr * 34 + px] = v.y;
    tile[(c4 + 2) * 340 + rr * 34 + px] = v.z;
    tile[(c4 + 3) * 340 + rr * 34 + px] = v.w;
  }
  __syncthreads();
  const int tx = tid & 31, ty = tid >> 5;      // col, row-pair
  float acc[2][3];
#pragma unroll
  for (int d = 0; d < 2; ++d)
#pragma unroll
    for (int c = 0; c < 3; ++c) acc[d][c] = 0.f;
#pragma unroll 2
  for (int ci = 0; ci < 32; ++ci) {
    float p[4][3];
#pragma unroll
    for (int r = 0; r < 4; ++r)
#pragma unroll
      for (int cx = 0; cx < 3; ++cx) {
        const int lx = tx + cx - 1;
        float v = 0.f;
        if ((unsigned)lx < 32u) v = tile[ci * 340 + (ty * 2 + r) * 34 + lx];
        p[r][cx] = v;
      }
#pragma unroll
    for (int ky = 0; ky < 3; ++ky)
#pragma unroll
      for (int kx = 0; kx < 3; ++kx) {
        const float* wp = w + ((ky * 3 + kx) * 32 + ci) * 3;
#pragma unroll
        for (int dy = 0; dy < 2; ++dy) {
          const float v = p[dy + ky][kx];
          acc[dy][0] = fmaf(v, wp[0], acc[dy][0]);
          acc[dy][1] = fmaf(v, wp[1], acc[dy][1]);
          acc[dy][2] = fmaf(v, wp[2], acc[dy][2]);
        }
      }
  }
#pragma unroll
  for (int dy = 0; dy < 2; ++dy) {
    const int oy = r0 + ty * 2 + dy;
    const size_t pidx = (size_t)b * 1024 + oy * 32 + tx;
    float e = 0.f;
#pragma unroll
    for (int c = 0; c < 3; ++c) {
      const float pre = acc[dy][c] + bb[c];
      float r;
      if (pre >= 0.f) {
        r = 1.f / (1.f + expf(-pre));
      } else {
        const float ex = expf(pre);
        r = ex / (1.f + ex);
      }
      const float dd = x[pidx * 3 + c] - r;
      e += dd * dd;
    }
    err[pidx] = e / 3.0f;
  }
}

// ---------------------------------------------------------------------------
// Otsu (faithful to reference) + mask write. block = 2 images.
// ---------------------------------------------------------------------------
__global__ __launch_bounds__(256) void k_otsu(const float* __restrict__ err,
                                              int* __restrict__ outmask) {
  __shared__ float e[2][1024];
  __shared__ float sig[2][81];
  __shared__ float opti[2];
  const int b0 = blockIdx.x * 2;
  const int tid = threadIdx.x;
  for (int f4 = tid; f4 < 512; f4 += 256) {
    const int img = f4 >> 8, idx = (f4 & 255) << 2;
    *(float4*)&e[img][idx] = *(const float4*)&err[(size_t)(b0 + img) * 1024 + idx];
  }
  __syncthreads();
  const int img = tid >> 7, j = tid & 127;
  if (j < 81) {
    const float t = (float)(0.1 + (double)j * 0.01);
    float n0 = 0.f, n1 = 0.f, s0 = 0.f, s1 = 0.f;
    for (int i = 0; i < 1024; ++i) {
      const float v = e[img][i];
      if (v < t) {
        if (v != 0.f) { n0 += 1.f; s0 += v; }
      } else {
        n1 += 1.f; s1 += v;
      }
    }
    const float nt = n0 + n1;
    float m0 = (s0 / 1024.f) * (nt / n0);
    if (m0 != m0) m0 = 0.f;
    float m1 = (s1 / 1024.f) * (nt / n1);
    if (m1 != m1) m1 = 0.f;
    const float p0 = n0 / nt, p1 = n1 / nt;
    const float dm = m0 - m1;
    sig[img][j] = p0 * p1 * (dm * dm);
  }
  __syncthreads();
  if (j == 0) {
    float smax = 0.f, op = 0.f;
    for (int jj = 0; jj < 81; ++jj) {
      const float sb = sig[img][jj];
      const float t = (float)(0.1 + (double)jj * 0.01);
      if (sb >= smax) { smax = sb; op = t; }
    }
    opti[img] = op;
  }
  __syncthreads();
#pragma unroll
  for (int q = 0; q < 8; ++q) {
    const int idx = tid + q * 256;             // 0..2047
    const int im = idx >> 10, p = idx & 1023;
    outmask[(size_t)(b0 + im) * 1024 + p] = (e[im][p] < opti[im]) ? 1 : 0;
  }
}

// ============================================================================
extern "C" void kernel_launch(void* const* d_in, const int* in_sizes, int n_in,
                              void* d_out, int out_size, void* d_ws, size_t ws_size,
                              hipStream_t stream) {
  (void)in_sizes; (void)n_in; (void)out_size;
  const float* x    = (const float*)d_in[0];
  const float* eps  = (const float*)d_in[1];
  const float* ew1  = (const float*)d_in[2];
  const float* eb1  = (const float*)d_in[3];
  const float* es1  = (const float*)d_in[4];
  const float* eo1  = (const float*)d_in[5];
  const float* ew2  = (const float*)d_in[6];
  const float* eb2  = (const float*)d_in[7];
  const float* es2  = (const float*)d_in[8];
  const float* eo2  = (const float*)d_in[9];
  const float* ew3  = (const float*)d_in[10];
  const float* eb3  = (const float*)d_in[11];
  const float* es3  = (const float*)d_in[12];
  const float* eo3  = (const float*)d_in[13];
  const float* wzm  = (const float*)d_in[14];
  const float* bzm  = (const float*)d_in[15];
  const float* wzl  = (const float*)d_in[16];
  const float* bzl  = (const float*)d_in[17];
  const float* dw   = (const float*)d_in[18];
  const float* db   = (const float*)d_in[19];
  const float* tw1  = (const float*)d_in[20];
  const float* tb1  = (const float*)d_in[21];
  const float* ds1  = (const float*)d_in[22];
  const float* do1  = (const float*)d_in[23];
  const float* tw2  = (const float*)d_in[24];
  const float* tb2  = (const float*)d_in[25];
  const float* ds2  = (const float*)d_in[26];
  const float* do2  = (const float*)d_in[27];
  const float* tw3  = (const float*)d_in[28];
  const float* tb3  = (const float*)d_in[29];
  const float* ds3  = (const float*)d_in[30];
  const float* do3  = (const float*)d_in[31];
  const float* tw4  = (const float*)d_in[32];
  const float* tb4  = (const float*)d_in[33];
  int* mask = (int*)d_out;

  // --- chunk size: largest C with C*233472 B workspace fitting ws_size ---
  // per-image slots (floats): P0=32768 (h1|d|t3), P1=8192 (h2|z|t1),
  //                           P2=16384 (h3|t2),  P3=1024 (err)
  const size_t per_img_bytes = 233472;
  int C = 64;
  const int cand[6] = {4096, 2048, 1024, 512, 256, 128};
  for (int i = 0; i < 6; ++i) {
    if ((size_t)cand[i] * per_img_bytes <= ws_size) { C = cand[i]; break; }
  }

  float* p0 = (float*)d_ws;                       // C*32768 floats
  float* p1 = p0 + (size_t)C * 32768;             // C*8192
  float* p2 = p1 + (size_t)C * 8192;              // C*16384
  float* p3 = p2 + (size_t)C * 16384;             // C*1024

  for (int c0 = 0; c0 < 4096; c0 += C) {
    const float* xc   = x   + (size_t)c0 * 3072;
    const float* epsc = eps + (size_t)c0 * 128;
    int*         mc   = mask + (size_t)c0 * 1024;
    float* h1 = p0;  float* dd = p0;  float* t3 = p0;
    float* h2 = p1;  float* zz = p1;  float* t1 = p1;
    float* h3 = p2;  float* t2 = p2;
    float* er = p3;

    k_conv1    <<<C,      256, 0, stream>>>(xc, ew1, eb1, es1, eo1, h1);
    k_conv2    <<<C / 2,  256, 0, stream>>>(h1, ew2, eb2, es2, eo2, h2);
    k_conv3    <<<C / 4,  256, 0, stream>>>(h2, ew3, eb3, es3, eo3, h3);
    k_fcz      <<<C / 16, 256, 0, stream>>>(h3, wzm, bzm, wzl, bzl, epsc, zz);
    k_fcdec    <<<C,      256, 0, stream>>>(zz, dw, db, dd);
    k_tconv1   <<<C,      256, 0, stream>>>(dd, tw1, tb1, ds1, do1, t1);
    k_tconv2   <<<C,      256, 0, stream>>>(t1, tw2, tb2, ds2, do2, t2);
    k_tconv3   <<<C,      256, 0, stream>>>(t2, tw3, tb3, ds3, do3, t3);
    k_tconv4err<<<C * 4,  128, 0, stream>>>(t3, tw4, tb4, xc, er);
    k_otsu     <<<C / 2,  256, 0, stream>>>(er, mc);
  }
}

// Round 3
// 4348.743 us; speedup vs baseline: 1.7784x; 1.7784x over previous
//
#include <hip/hip_runtime.h>
#include <cstdint>
#include <cstddef>

// ============================================================================
// disciminativeAno: fp32 VAE forward + Otsu mask on gfx950.
// R3: occupancy-focused rework. LDS <= 32-36 KB per 256-thr block (>=16-20
// waves/CU) or 512-thr blocks on 64 KB. Weight streams stay wave-uniform
// (readfirstlane -> s_load). Accumulator tiles sized to keep VGPR <= ~128.
// ============================================================================

// ---------------------------------------------------------------------------
// conv1: x[C,32,32,3] -> h1[C,16,16,32], 5x5 s2 SAME (pad lo=1), relu(+b)*s+o
// ---------------------------------------------------------------------------
__global__ __launch_bounds__(256) void k_conv1(const float* __restrict__ x,
    const float* __restrict__ w, const float* __restrict__ bb,
    const float* __restrict__ sc, const float* __restrict__ of,
    float* __restrict__ out) {
  const int b = blockIdx.x;
  const int pos = threadIdx.x;          // 16x16 output positions
  const int oy = pos >> 4, ox = pos & 15;
  float acc[32];
#pragma unroll
  for (int c = 0; c < 32; ++c) acc[c] = 0.f;
  const float* xb = x + (size_t)b * 3072;
#pragma unroll 1
  for (int ky = 0; ky < 5; ++ky) {
    const int iy = 2 * oy - 1 + ky;
    if ((unsigned)iy >= 32u) continue;
#pragma unroll 1
    for (int kx = 0; kx < 5; ++kx) {
      const int ix = 2 * ox - 1 + kx;
      if ((unsigned)ix >= 32u) continue;
      const float* xp = xb + (iy * 32 + ix) * 3;
#pragma unroll
      for (int ci = 0; ci < 3; ++ci) {
        const float v = xp[ci];
        const float* wp = w + ((ky * 5 + kx) * 3 + ci) * 32;
#pragma unroll
        for (int c = 0; c < 32; ++c) acc[c] = fmaf(v, wp[c], acc[c]);
      }
    }
  }
  float* op = out + ((size_t)b * 256 + pos) * 32;
#pragma unroll
  for (int c = 0; c < 32; ++c) {
    const float v = fmaxf(acc[c] + bb[c], 0.f);
    op[c] = v * sc[c] + of[c];
  }
}

// ---------------------------------------------------------------------------
// conv2: h1[C,16,16,32] -> h2[C,8,8,64], 5x5 s2 SAME (pad lo=1)
// v2: 1 img/block (32 KB LDS -> 5 blocks/CU = 20 waves), 256 thr =
//     64 pos x 4 co-groups(16 co), acc[16].
// ---------------------------------------------------------------------------
__global__ __launch_bounds__(256) void k_conv2(const float* __restrict__ in,
    const float* __restrict__ w, const float* __restrict__ bb,
    const float* __restrict__ sc, const float* __restrict__ of,
    float* __restrict__ out) {
  __shared__ float tile[8192];           // 32 KB, XOR swizzled
  const int b = blockIdx.x;
  const int tid = threadIdx.x;
#pragma unroll
  for (int q = 0; q < 8; ++q) {
    const int f4 = tid + q * 256;        // 2048 f4
    const int pix = f4 >> 3, c4 = (f4 & 7) << 2;
    const float4 v = ((const float4*)(in + (size_t)b * 8192))[f4];
    const int s = ((pix >> 4) * 5 + (pix & 15)) & 31;
    float* dst = &tile[pix * 32];
    dst[(c4 + 0) ^ s] = v.x; dst[(c4 + 1) ^ s] = v.y;
    dst[(c4 + 2) ^ s] = v.z; dst[(c4 + 3) ^ s] = v.w;
  }
  __syncthreads();
  const int pos = tid & 63;
  const int ch = __builtin_amdgcn_readfirstlane(tid >> 6) * 16;
  const int oy = pos >> 3, ox = pos & 7;
  float acc[16];
#pragma unroll
  for (int c = 0; c < 16; ++c) acc[c] = 0.f;
#pragma unroll 1
  for (int ky = 0; ky < 5; ++ky) {
    const int iy = 2 * oy - 1 + ky;
#pragma unroll 1
    for (int kx = 0; kx < 5; ++kx) {
      const int ix = 2 * ox - 1 + kx;
      const bool valid = ((unsigned)iy < 16u) && ((unsigned)ix < 16u);
      const int pix = valid ? (iy * 16 + ix) : 0;
      const int s = ((pix >> 4) * 5 + (pix & 15)) & 31;
      const float* tp = &tile[pix * 32];
      const float* wrow = w + ((ky * 5 + kx) * 32) * 64 + ch;
#pragma unroll 4
      for (int ci = 0; ci < 32; ++ci) {
        float v = tp[ci ^ s];
        v = valid ? v : 0.f;
        const float* wp = wrow + ci * 64;
#pragma unroll
        for (int c = 0; c < 16; ++c) acc[c] = fmaf(v, wp[c], acc[c]);
      }
    }
  }
  float* op = out + ((size_t)b * 64 + pos) * 64 + ch;
#pragma unroll
  for (int c = 0; c < 16; ++c) {
    const float v = fmaxf(acc[c] + bb[ch + c], 0.f);
    op[c] = v * sc[ch + c] + of[ch + c];
  }
}

// ---------------------------------------------------------------------------
// conv3: h2[C,8,8,64] -> h3[C,4,4,128], 5x5 s2 SAME (pad lo=1)
// v2: 512 thr, 4 img (64 KB) -> 2 blocks x 8 waves = 16 waves/CU.
//     thread = (img,pos) lane x 8 co-groups(16 co), acc[16].
// ---------------------------------------------------------------------------
__global__ __launch_bounds__(512) void k_conv3(const float* __restrict__ in,
    const float* __restrict__ w, const float* __restrict__ bb,
    const float* __restrict__ sc, const float* __restrict__ of,
    float* __restrict__ out) {
  __shared__ float tile[4 * 4096];       // 64 KB
  const int b0 = blockIdx.x * 4;
  const int tid = threadIdx.x;
#pragma unroll
  for (int q = 0; q < 8; ++q) {
    const int f4 = tid + q * 512;        // 4096 f4
    const int img = f4 >> 10, rem = f4 & 1023;
    const int pix = rem >> 4, c4 = (rem & 15) << 2;
    const float4 v = ((const float4*)(in + (size_t)(b0 + img) * 4096))[rem];
    const int s = ((pix >> 3) * 5 + (pix & 7) + img * 9) & 31;
    float* dst = &tile[img * 4096 + pix * 64];
    dst[(c4 + 0) ^ s] = v.x; dst[(c4 + 1) ^ s] = v.y;
    dst[(c4 + 2) ^ s] = v.z; dst[(c4 + 3) ^ s] = v.w;
  }
  __syncthreads();
  const int lane = tid & 63;
  const int pos = lane & 15, img = lane >> 4;
  const int ch = __builtin_amdgcn_readfirstlane(tid >> 6) * 16;
  const int oy = pos >> 2, ox = pos & 3;
  float acc[16];
#pragma unroll
  for (int c = 0; c < 16; ++c) acc[c] = 0.f;
  const float* tb = &tile[img * 4096];
#pragma unroll 1
  for (int ky = 0; ky < 5; ++ky) {
    const int iy = 2 * oy - 1 + ky;
#pragma unroll 1
    for (int kx = 0; kx < 5; ++kx) {
      const int ix = 2 * ox - 1 + kx;
      const bool valid = ((unsigned)iy < 8u) && ((unsigned)ix < 8u);
      const int pix = valid ? (iy * 8 + ix) : 0;
      const int s = ((pix >> 3) * 5 + (pix & 7) + img * 9) & 31;
      const float* tp = tb + pix * 64;
      const float* wrow = w + ((ky * 5 + kx) * 64) * 128 + ch;
#pragma unroll 4
      for (int ci = 0; ci < 64; ++ci) {
        float v = tp[ci ^ s];
        v = valid ? v : 0.f;
        const float* wp = wrow + ci * 128;
#pragma unroll
        for (int c = 0; c < 16; ++c) acc[c] = fmaf(v, wp[c], acc[c]);
      }
    }
  }
  float* op = out + ((size_t)(b0 + img) * 16 + pos) * 128 + ch;
#pragma unroll
  for (int c = 0; c < 16; ++c) {
    const float v = fmaxf(acc[c] + bb[ch + c], 0.f);
    op[c] = v * sc[ch + c] + of[ch + c];
  }
}

// ---------------------------------------------------------------------------
// fc_z: h3[C,2048] -> z[C,128]
// v2: 4 img/block (grid C/4) -> more blocks, tiny LDS, 32 waves/CU.
// ---------------------------------------------------------------------------
__global__ __launch_bounds__(256) void k_fcz(const float* __restrict__ h3,
    const float* __restrict__ wzm, const float* __restrict__ bzm,
    const float* __restrict__ wzl, const float* __restrict__ bzl,
    const float* __restrict__ eps, float* __restrict__ z) {
  __shared__ float a[4 * 256];
  const int ib = blockIdx.x * 4;
  const int tid = threadIdx.x;
  const int co = tid & 127;
  const int grp = __builtin_amdgcn_readfirstlane(tid >> 7);  // 2 imgs each
  float am[2], al[2];
#pragma unroll
  for (int i = 0; i < 2; ++i) { am[i] = 0.f; al[i] = 0.f; }
  for (int kc = 0; kc < 2048; kc += 256) {
    __syncthreads();
    {
      const int r = tid >> 6, c4 = (tid & 63) << 2;
      *(float4*)&a[r * 256 + c4] =
          *(const float4*)&h3[(size_t)(ib + r) * 2048 + kc + c4];
    }
    __syncthreads();
#pragma unroll 4
    for (int k = 0; k < 256; k += 4) {
      float wm[4], wl[4];
#pragma unroll
      for (int q = 0; q < 4; ++q) {
        wm[q] = wzm[(size_t)(kc + k + q) * 128 + co];
        wl[q] = wzl[(size_t)(kc + k + q) * 128 + co];
      }
#pragma unroll
      for (int i = 0; i < 2; ++i) {
        const float4 av = *(const float4*)&a[(grp * 2 + i) * 256 + k];
        am[i] = fmaf(av.x, wm[0], am[i]); am[i] = fmaf(av.y, wm[1], am[i]);
        am[i] = fmaf(av.z, wm[2], am[i]); am[i] = fmaf(av.w, wm[3], am[i]);
        al[i] = fmaf(av.x, wl[0], al[i]); al[i] = fmaf(av.y, wl[1], al[i]);
        al[i] = fmaf(av.z, wl[2], al[i]); al[i] = fmaf(av.w, wl[3], al[i]);
      }
    }
  }
#pragma unroll
  for (int i = 0; i < 2; ++i) {
    const int row = ib + grp * 2 + i;
    const float zm = fmaxf(am[i] + bzm[co], 0.f);
    const float zl = fmaxf(al[i] + bzl[co], 0.f);
    z[(size_t)row * 128 + co] = zm + expf(0.5f * zl) * eps[(size_t)row * 128 + co];
  }
}

// ---------------------------------------------------------------------------
// fc_dec: z[C,128] @ dw[128,8192] + db -> relu -> d[C,8192]
// ---------------------------------------------------------------------------
__global__ __launch_bounds__(256) void k_fcdec(const float* __restrict__ z,
    const float* __restrict__ dw, const float* __restrict__ db,
    float* __restrict__ out) {
  __shared__ float zt[64 * 128];         // 32 KB
  const int bid = blockIdx.x;
  const int m0 = (bid >> 6) * 64;
  const int n0 = (bid & 63) * 128;
  const int tid = threadIdx.x;
#pragma unroll
  for (int q = 0; q < 8; ++q) {
    const int f4 = tid + q * 256;        // 2048 f4
    const int img = f4 >> 5, c4 = (f4 & 31) << 2;
    const float4 v = *(const float4*)&z[(size_t)(m0 + img) * 128 + c4];
    const int s = img & 31;
    float* dst = &zt[img * 128];
    dst[(c4 + 0) ^ s] = v.x; dst[(c4 + 1) ^ s] = v.y;
    dst[(c4 + 2) ^ s] = v.z; dst[(c4 + 3) ^ s] = v.w;
  }
  __syncthreads();
  const int img = tid & 63;
  const int grp = __builtin_amdgcn_readfirstlane(tid >> 6);
  const int nb = n0 + grp * 32;
  float acc[32];
#pragma unroll
  for (int c = 0; c < 32; ++c) acc[c] = 0.f;
  const float* zrow = &zt[img * 128];
  const int s = img & 31;
#pragma unroll 4
  for (int k = 0; k < 128; ++k) {
    const float v = zrow[k ^ s];
    const float* wp = dw + (size_t)k * 8192 + nb;
#pragma unroll
    for (int c = 0; c < 32; ++c) acc[c] = fmaf(v, wp[c], acc[c]);
  }
  float* op = out + (size_t)(m0 + img) * 8192 + nb;
#pragma unroll
  for (int c = 0; c < 32; ++c) op[c] = fmaxf(acc[c] + db[nb + c], 0.f);
}

// ---------------------------------------------------------------------------
// convT1: 1x1 s1: d[C,8,8,128] -> t1[C,8,8,128]
// ---------------------------------------------------------------------------
__global__ __launch_bounds__(256) void k_tconv1(const float* __restrict__ in,
    const float* __restrict__ w, const float* __restrict__ bb,
    const float* __restrict__ sc, const float* __restrict__ of,
    float* __restrict__ out) {
  __shared__ float tile[8192];           // 32 KB
  const int b = blockIdx.x;
  const int tid = threadIdx.x;
#pragma unroll
  for (int q = 0; q < 8; ++q) {
    const int f4 = tid + q * 256;
    const int pix = f4 >> 5, c4 = (f4 & 31) << 2;
    const float4 v = ((const float4*)(in + (size_t)b * 8192))[f4];
    const int s = pix & 31;
    float* dst = &tile[pix * 128];
    dst[(c4 + 0) ^ s] = v.x; dst[(c4 + 1) ^ s] = v.y;
    dst[(c4 + 2) ^ s] = v.z; dst[(c4 + 3) ^ s] = v.w;
  }
  __syncthreads();
  const int pos = tid & 63;
  const int ch = __builtin_amdgcn_readfirstlane((tid >> 6) * 32);
  const float* trow = &tile[pos * 128];
  const int s = pos & 31;
  float acc[32];
#pragma unroll
  for (int c = 0; c < 32; ++c) acc[c] = 0.f;
#pragma unroll 4
  for (int ci = 0; ci < 128; ++ci) {
    const float v = trow[ci ^ s];
    const float* wp = w + ci * 128 + ch;
#pragma unroll
    for (int c = 0; c < 32; ++c) acc[c] = fmaf(v, wp[c], acc[c]);
  }
  float* op = out + ((size_t)b * 64 + pos) * 128 + ch;
#pragma unroll
  for (int c = 0; c < 32; ++c) {
    const float v = fmaxf(acc[c] + bb[ch + c], 0.f);
    op[c] = v * sc[ch + c] + of[ch + c];
  }
}

// ---------------------------------------------------------------------------
// convT2: 3x3 s2 SAME transpose (UNFLIPPED, lhs-dilated, pad (2,1)):
//   out[2j+0] += in[j-1]*w[0] + in[j]*w[2];  out[2j+1] += in[j]*w[1]
// v2: 32 KB exactly via XOR swizzle -> 5 blocks/CU.
// ---------------------------------------------------------------------------
__global__ __launch_bounds__(256) void k_tconv2(const float* __restrict__ in,
    const float* __restrict__ w, const float* __restrict__ bb,
    const float* __restrict__ sc, const float* __restrict__ of,
    float* __restrict__ out) {
  __shared__ float tile[64 * 128];       // 32 KB, XOR swizzled
  const int b = blockIdx.x;
  const int tid = threadIdx.x;
#pragma unroll
  for (int q = 0; q < 8; ++q) {
    const int f4 = tid + q * 256;
    const int pix = f4 >> 5, c4 = (f4 & 31) << 2;
    const float4 v = ((const float4*)(in + (size_t)b * 8192))[f4];
    const int s = ((pix >> 3) * 5 + (pix & 7)) & 31;
    float* dst = &tile[pix * 128];
    dst[(c4 + 0) ^ s] = v.x; dst[(c4 + 1) ^ s] = v.y;
    dst[(c4 + 2) ^ s] = v.z; dst[(c4 + 3) ^ s] = v.w;
  }
  __syncthreads();
  const int lane = tid & 63;
  const int ch = __builtin_amdgcn_readfirstlane((tid >> 6) * 16);
  const int jy = lane >> 3, jx = lane & 7;
  float acc[4][16];
#pragma unroll
  for (int p = 0; p < 4; ++p)
#pragma unroll
    for (int c = 0; c < 16; ++c) acc[p][c] = 0.f;
  // UNFLIPPED pairing: DY=1<->KY=0, DY=0<->KY=2 (even phase); DY=0<->KY=1 (odd)
  const int DY[9]  = {1,1,0,0,1,0,0,0,0};
  const int DX[9]  = {1,0,1,0,0,0,1,0,0};
  const int KYt[9] = {0,0,2,2,0,2,1,1,1};
  const int KXt[9] = {0,2,0,2,1,1,0,2,1};
  const int PHt[9] = {0,0,0,0,1,1,2,2,3};
#pragma unroll
  for (int t = 0; t < 9; ++t) {
    const int sy = jy - DY[t], sx = jx - DX[t];
    const bool valid = (sy >= 0) && (sx >= 0);
    const int pix = valid ? (sy * 8 + sx) : 0;
    const int s = ((pix >> 3) * 5 + (pix & 7)) & 31;
    const float* tp = &tile[pix * 128];
    const float* wrow = w + ((KYt[t] * 3 + KXt[t]) * 128) * 64 + ch;
#pragma unroll 4
    for (int ci = 0; ci < 128; ++ci) {
      float v = tp[ci ^ s];
      v = valid ? v : 0.f;
      const float* wp = wrow + ci * 64;
#pragma unroll
      for (int c = 0; c < 16; ++c)
        acc[PHt[t]][c] = fmaf(v, wp[c], acc[PHt[t]][c]);
    }
  }
#pragma unroll
  for (int py = 0; py < 2; ++py)
#pragma unroll
    for (int px = 0; px < 2; ++px) {
      const int oy = 2 * jy + py, ox = 2 * jx + px;
      float* op = out + (((size_t)b * 16 + oy) * 16 + ox) * 64 + ch;
#pragma unroll
      for (int c = 0; c < 16; ++c) {
        const float v = fmaxf(acc[py * 2 + px][c] + bb[ch + c], 0.f);
        op[c] = v * sc[ch + c] + of[ch + c];
      }
    }
}

// ---------------------------------------------------------------------------
// convT3: 3x3 s2 SAME transpose (unflipped): t2[C,16,16,64] -> t3[C,32,32,32]
// v2: 8-input-row slab + 1 halo row staged (36 KB -> 4 blocks/CU),
//     thread = in-pos(128) x co-half(16), acc[4][16] (64 VGPR).
//     Top halo row is zero-filled when r0==0, so only sx needs a validity check.
// ---------------------------------------------------------------------------
__global__ __launch_bounds__(256) void k_tconv3(const float* __restrict__ in,
    const float* __restrict__ w, const float* __restrict__ bb,
    const float* __restrict__ sc, const float* __restrict__ of,
    float* __restrict__ out) {
  __shared__ float tile[9 * 16 * 64];    // 36 KB: staged rows r0-1 .. r0+7
  const int b = blockIdx.x >> 1;
  const int r0 = (blockIdx.x & 1) * 8;
  const int tid = threadIdx.x;
#pragma unroll
  for (int q = 0; q < 9; ++q) {
    const int f4 = tid + q * 256;        // 2304 f4
    const int rr = f4 >> 8, rem = f4 & 255;
    const int col = rem >> 4, c4 = (rem & 15) << 2;
    const int gy = r0 - 1 + rr;
    float4 v = make_float4(0.f, 0.f, 0.f, 0.f);
    if (gy >= 0)
      v = *(const float4*)&in[(((size_t)b * 16 + gy) * 16 + col) * 64 + c4];
    const int s = (rr * 5 + col) & 31;
    float* dst = &tile[(rr * 16 + col) * 64];
    dst[(c4 + 0) ^ s] = v.x; dst[(c4 + 1) ^ s] = v.y;
    dst[(c4 + 2) ^ s] = v.z; dst[(c4 + 3) ^ s] = v.w;
  }
  __syncthreads();
  const int pos = tid & 127;
  const int jy = pos >> 4, jx = pos & 15;
  const int ch = __builtin_amdgcn_readfirstlane(tid >> 7) * 16;
  float acc[4][16];
#pragma unroll
  for (int p = 0; p < 4; ++p)
#pragma unroll
    for (int c = 0; c < 16; ++c) acc[p][c] = 0.f;
  const int DY[9]  = {1,1,0,0,1,0,0,0,0};
  const int DX[9]  = {1,0,1,0,0,0,1,0,0};
  const int KYt[9] = {0,0,2,2,0,2,1,1,1};
  const int KXt[9] = {0,2,0,2,1,1,0,2,1};
  const int PHt[9] = {0,0,0,0,1,1,2,2,3};
#pragma unroll
  for (int t = 0; t < 9; ++t) {
    const int syst = jy + 1 - DY[t];     // staged row index, always in [0,8]
    const int sx = jx - DX[t];
    const bool valid = (sx >= 0);        // halo row is zero-filled
    const int sxc = valid ? sx : 0;
    const int s = (syst * 5 + sxc) & 31;
    const float* tp = &tile[(syst * 16 + sxc) * 64];
    const float* wrow = w + ((KYt[t] * 3 + KXt[t]) * 64) * 32 + ch;
#pragma unroll 2
    for (int ci = 0; ci < 64; ++ci) {
      float v = tp[ci ^ s];
      v = valid ? v : 0.f;
      const float* wp = wrow + ci * 32;
#pragma unroll
      for (int c = 0; c < 16; ++c)
        acc[PHt[t]][c] = fmaf(v, wp[c], acc[PHt[t]][c]);
    }
  }
  const int gy = r0 + jy;
#pragma unroll
  for (int py = 0; py < 2; ++py)
#pragma unroll
    for (int px = 0; px < 2; ++px) {
      const int oy = 2 * gy + py, ox = 2 * jx + px;
      float* op = out + (((size_t)b * 32 + oy) * 32 + ox) * 32 + ch;
#pragma unroll
      for (int c = 0; c < 16; ++c) {
        const float v = fmaxf(acc[py * 2 + px][c] + bb[ch + c], 0.f);
        op[c] = v * sc[ch + c] + of[ch + c];
      }
    }
}

// ---------------------------------------------------------------------------
// convT4 (3x3 s1 SAME, pad (1,1), unflipped) + sigmoid + per-pixel error.
// ---------------------------------------------------------------------------
__global__ __launch_bounds__(128) void k_tconv4err(const float* __restrict__ t3,
    const float* __restrict__ w, const float* __restrict__ bb,
    const float* __restrict__ x, float* __restrict__ err) {
  __shared__ float tile[32 * 340];       // [ci][row(10)*34 + col] = 43.5 KB
  const int b = blockIdx.x >> 2;
  const int r0 = (blockIdx.x & 3) * 8;
  const int tid = threadIdx.x;
  for (int f4 = tid; f4 < 2560; f4 += 128) {
    const int rr = f4 >> 8, rem = f4 & 255;
    const int px = rem >> 3, c4 = (rem & 7) << 2;
    const int gy = r0 - 1 + rr;
    float4 v = make_float4(0.f, 0.f, 0.f, 0.f);
    if ((unsigned)gy < 32u)
      v = *(const float4*)&t3[(((size_t)b * 32 + gy) * 32 + px) * 32 + c4];
    tile[(c4 + 0) * 340 + rr * 34 + px] = v.x;
    tile[(c4 + 1) * 340 + rr * 34 + px] = v.y;
    tile[(c4 + 2) * 340 + rr * 34 + px] = v.z;
    tile[(c4 + 3) * 340 + rr * 34 + px] = v.w;
  }
  __syncthreads();
  const int tx = tid & 31, ty = tid >> 5;      // col, row-pair
  float acc[2][3];
#pragma unroll
  for (int d = 0; d < 2; ++d)
#pragma unroll
    for (int c = 0; c < 3; ++c) acc[d][c] = 0.f;
#pragma unroll 2
  for (int ci = 0; ci < 32; ++ci) {
    float p[4][3];
#pragma unroll
    for (int r = 0; r < 4; ++r)
#pragma unroll
      for (int cx = 0; cx < 3; ++cx) {
        const int lx = tx + cx - 1;
        float v = 0.f;
        if ((unsigned)lx < 32u) v = tile[ci * 340 + (ty * 2 + r) * 34 + lx];
        p[r][cx] = v;
      }
#pragma unroll
    for (int ky = 0; ky < 3; ++ky)
#pragma unroll
      for (int kx = 0; kx < 3; ++kx) {
        const float* wp = w + ((ky * 3 + kx) * 32 + ci) * 3;
#pragma unroll
        for (int dy = 0; dy < 2; ++dy) {
          const float v = p[dy + ky][kx];
          acc[dy][0] = fmaf(v, wp[0], acc[dy][0]);
          acc[dy][1] = fmaf(v, wp[1], acc[dy][1]);
          acc[dy][2] = fmaf(v, wp[2], acc[dy][2]);
        }
      }
  }
#pragma unroll
  for (int dy = 0; dy < 2; ++dy) {
    const int oy = r0 + ty * 2 + dy;
    const size_t pidx = (size_t)b * 1024 + oy * 32 + tx;
    float e = 0.f;
#pragma unroll
    for (int c = 0; c < 3; ++c) {
      const float pre = acc[dy][c] + bb[c];
      float r;
      if (pre >= 0.f) {
        r = 1.f / (1.f + expf(-pre));
      } else {
        const float ex = expf(pre);
        r = ex / (1.f + ex);
      }
      const float dd = x[pidx * 3 + c] - r;
      e += dd * dd;
    }
    err[pidx] = e / 3.0f;
  }
}

// ---------------------------------------------------------------------------
// Otsu (faithful to reference) + mask write. block = 2 images.
// ---------------------------------------------------------------------------
__global__ __launch_bounds__(256) void k_otsu(const float* __restrict__ err,
                                              int* __restrict__ outmask) {
  __shared__ float e[2][1024];
  __shared__ float sig[2][81];
  __shared__ float opti[2];
  const int b0 = blockIdx.x * 2;
  const int tid = threadIdx.x;
  for (int f4 = tid; f4 < 512; f4 += 256) {
    const int img = f4 >> 8, idx = (f4 & 255) << 2;
    *(float4*)&e[img][idx] = *(const float4*)&err[(size_t)(b0 + img) * 1024 + idx];
  }
  __syncthreads();
  const int img = tid >> 7, j = tid & 127;
  if (j < 81) {
    const float t = (float)(0.1 + (double)j * 0.01);
    float n0 = 0.f, n1 = 0.f, s0 = 0.f, s1 = 0.f;
    for (int i = 0; i < 1024; ++i) {
      const float v = e[img][i];
      if (v < t) {
        if (v != 0.f) { n0 += 1.f; s0 += v; }
      } else {
        n1 += 1.f; s1 += v;
      }
    }
    const float nt = n0 + n1;
    float m0 = (s0 / 1024.f) * (nt / n0);
    if (m0 != m0) m0 = 0.f;
    float m1 = (s1 / 1024.f) * (nt / n1);
    if (m1 != m1) m1 = 0.f;
    const float p0 = n0 / nt, p1 = n1 / nt;
    const float dm = m0 - m1;
    sig[img][j] = p0 * p1 * (dm * dm);
  }
  __syncthreads();
  if (j == 0) {
    float smax = 0.f, op = 0.f;
    for (int jj = 0; jj < 81; ++jj) {
      const float sb = sig[img][jj];
      const float t = (float)(0.1 + (double)jj * 0.01);
      if (sb >= smax) { smax = sb; op = t; }
    }
    opti[img] = op;
  }
  __syncthreads();
#pragma unroll
  for (int q = 0; q < 8; ++q) {
    const int idx = tid + q * 256;             // 0..2047
    const int im = idx >> 10, p = idx & 1023;
    outmask[(size_t)(b0 + im) * 1024 + p] = (e[im][p] < opti[im]) ? 1 : 0;
  }
}

// ============================================================================
extern "C" void kernel_launch(void* const* d_in, const int* in_sizes, int n_in,
                              void* d_out, int out_size, void* d_ws, size_t ws_size,
                              hipStream_t stream) {
  (void)in_sizes; (void)n_in; (void)out_size;
  const float* x    = (const float*)d_in[0];
  const float* eps  = (const float*)d_in[1];
  const float* ew1  = (const float*)d_in[2];
  const float* eb1  = (const float*)d_in[3];
  const float* es1  = (const float*)d_in[4];
  const float* eo1  = (const float*)d_in[5];
  const float* ew2  = (const float*)d_in[6];
  const float* eb2  = (const float*)d_in[7];
  const float* es2  = (const float*)d_in[8];
  const float* eo2  = (const float*)d_in[9];
  const float* ew3  = (const float*)d_in[10];
  const float* eb3  = (const float*)d_in[11];
  const float* es3  = (const float*)d_in[12];
  const float* eo3  = (const float*)d_in[13];
  const float* wzm  = (const float*)d_in[14];
  const float* bzm  = (const float*)d_in[15];
  const float* wzl  = (const float*)d_in[16];
  const float* bzl  = (const float*)d_in[17];
  const float* dw   = (const float*)d_in[18];
  const float* db   = (const float*)d_in[19];
  const float* tw1  = (const float*)d_in[20];
  const float* tb1  = (const float*)d_in[21];
  const float* ds1  = (const float*)d_in[22];
  const float* do1  = (const float*)d_in[23];
  const float* tw2  = (const float*)d_in[24];
  const float* tb2  = (const float*)d_in[25];
  const float* ds2  = (const float*)d_in[26];
  const float* do2  = (const float*)d_in[27];
  const float* tw3  = (const float*)d_in[28];
  const float* tb3  = (const float*)d_in[29];
  const float* ds3  = (const float*)d_in[30];
  const float* do3  = (const float*)d_in[31];
  const float* tw4  = (const float*)d_in[32];
  const float* tb4  = (const float*)d_in[33];
  int* mask = (int*)d_out;

  // --- chunk size: largest C with C*233472 B workspace fitting ws_size ---
  // per-image slots (floats): P0=32768 (h1|d|t3), P1=8192 (h2|z|t1),
  //                           P2=16384 (h3|t2),  P3=1024 (err)
  const size_t per_img_bytes = 233472;
  int C = 64;
  const int cand[6] = {4096, 2048, 1024, 512, 256, 128};
  for (int i = 0; i < 6; ++i) {
    if ((size_t)cand[i] * per_img_bytes <= ws_size) { C = cand[i]; break; }
  }

  float* p0 = (float*)d_ws;                       // C*32768 floats
  float* p1 = p0 + (size_t)C * 32768;             // C*8192
  float* p2 = p1 + (size_t)C * 8192;              // C*16384
  float* p3 = p2 + (size_t)C * 16384;             // C*1024

  for (int c0 = 0; c0 < 4096; c0 += C) {
    const float* xc   = x   + (size_t)c0 * 3072;
    const float* epsc = eps + (size_t)c0 * 128;
    int*         mc   = mask + (size_t)c0 * 1024;
    float* h1 = p0;  float* dd = p0;  float* t3 = p0;
    float* h2 = p1;  float* zz = p1;  float* t1 = p1;
    float* h3 = p2;  float* t2 = p2;
    float* er = p3;

    k_conv1    <<<C,      256, 0, stream>>>(xc, ew1, eb1, es1, eo1, h1);
    k_conv2    <<<C,      256, 0, stream>>>(h1, ew2, eb2, es2, eo2, h2);
    k_conv3    <<<C / 4,  512, 0, stream>>>(h2, ew3, eb3, es3, eo3, h3);
    k_fcz      <<<C / 4,  256, 0, stream>>>(h3, wzm, bzm, wzl, bzl, epsc, zz);
    k_fcdec    <<<C,      256, 0, stream>>>(zz, dw, db, dd);
    k_tconv1   <<<C,      256, 0, stream>>>(dd, tw1, tb1, ds1, do1, t1);
    k_tconv2   <<<C,      256, 0, stream>>>(t1, tw2, tb2, ds2, do2, t2);
    k_tconv3   <<<C * 2,  256, 0, stream>>>(t2, tw3, tb3, ds3, do3, t3);
    k_tconv4err<<<C * 4,  128, 0, stream>>>(t3, tw4, tb4, xc, er);
    k_otsu     <<<C / 2,  256, 0, stream>>>(er, mc);
  }
}